// Round 25
// baseline (94.359 us; speedup 1.0000x reference)
//
#include <hip/hip_runtime.h>

#define EPSV 1e-5f

typedef __attribute__((ext_vector_type(8))) short bf16x8;
typedef __attribute__((ext_vector_type(4))) float f32x4;

__device__ __forceinline__ unsigned short f2bf(float x) {
  unsigned u = __float_as_uint(x);
  unsigned r = (u + 0x7FFFu + ((u >> 16) & 1u)) >> 16;
  return (unsigned short)r;
}

__device__ __forceinline__ unsigned pack2bf(float a, float b) {
  return (unsigned)f2bf(a) | ((unsigned)f2bf(b) << 16);
}

__device__ __forceinline__ void bf8_decode(int4 v, float* dst) {
  unsigned u0 = (unsigned)v.x, u1 = (unsigned)v.y, u2 = (unsigned)v.z, u3 = (unsigned)v.w;
  dst[0] = __uint_as_float(u0 << 16); dst[1] = __uint_as_float(u0 & 0xffff0000u);
  dst[2] = __uint_as_float(u1 << 16); dst[3] = __uint_as_float(u1 & 0xffff0000u);
  dst[4] = __uint_as_float(u2 << 16); dst[5] = __uint_as_float(u2 & 0xffff0000u);
  dst[6] = __uint_as_float(u3 << 16); dst[7] = __uint_as_float(u3 & 0xffff0000u);
}

__device__ __forceinline__ float block_reduce_sum(float v, float* lds) {
  #pragma unroll
  for (int off = 32; off > 0; off >>= 1) v += __shfl_down(v, off, 64);
  int lane = threadIdx.x & 63;
  int wid  = threadIdx.x >> 6;
  __syncthreads();
  if (lane == 0) lds[wid] = v;
  __syncthreads();
  float r = 0.f;
  if (threadIdx.x == 0) {
    int nw = blockDim.x >> 6;
    for (int i = 0; i < nw; ++i) r += lds[i];
  }
  return r;
}

// K1 v8: one 512-thread block per image; single x stage shared by both
// channel halves (waves 0-3 -> co 0-7, waves 4-7 -> co 8-15).
// conv1 + stats partials + y1 bf16 planar store. Block 0 builds wA.
__global__ __launch_bounds__(512) void k1_conv1_stats(
    const float* __restrict__ x, const float* __restrict__ w1, const float* __restrict__ b1,
    float* __restrict__ partials /* [16][2][1024] */,
    const float* __restrict__ w2, short* __restrict__ wA, short* __restrict__ y1) {
  __shared__ float xt[3468];
  __shared__ float red[128];
  const int tid = threadIdx.x, b = blockIdx.x;

  if (b == 0) {  // one-time A-fragment build: all 18432 entries
    for (int i = tid; i < 18432; i += 512) {
      int e = i & 7, l = (i >> 3) & 63, p = (i >> 9) & 1, m = (i >> 10) & 1, s = i >> 11;
      int co = m * 16 + (l & 15);
      int ci = (l >> 4) * 8 + e;
      int ky = s / 3, kx = s - ky * 3;
      float wv = w2[((co * 32 + ci) * 3 + ky) * 3 + kx];
      unsigned short h = f2bf(wv);
      unsigned short val = p ? f2bf(wv - __uint_as_float((unsigned)h << 16)) : h;
      wA[i] = (short)val;
    }
  }

  // Stage x[b] (3x32x32) into zero-padded [3][34][34] with 512 threads.
  {
    float4* t4 = (float4*)xt;
    for (int idx = tid; idx < 867; idx += 512) t4[idx] = make_float4(0.f, 0.f, 0.f, 0.f);
  }
  __syncthreads();
  {
    const float4* x4 = (const float4*)(x + b * 3072);
    for (int e4 = tid; e4 < 768; e4 += 512) {
      float4 v = x4[e4];
      int w0 = e4 * 4;
      int ch = w0 >> 10;
      int pos = w0 & 1023;
      int r = pos >> 5, c = pos & 31;
      int base = ch * 1156 + (r + 1) * 34 + (c + 1);
      xt[base] = v.x; xt[base + 1] = v.y; xt[base + 2] = v.z; xt[base + 3] = v.w;
    }
  }
  __syncthreads();

  const int u = tid & 255;              // spatial thread
  const int chalf = tid >> 8;           // 0: co 0-7, 1: co 8-15
  const int co0 = chalf * 8;
  const int c = u & 31, r0 = (u >> 5) * 4;
  const int sbase = r0 * 34 + c;
  float xv[54];
  #pragma unroll
  for (int ci = 0; ci < 3; ++ci)
    #pragma unroll
    for (int dr = 0; dr < 6; ++dr)
      #pragma unroll
      for (int dx = 0; dx < 3; ++dx)
        xv[ci * 18 + dr * 3 + dx] = xt[ci * 1156 + sbase + dr * 34 + dx];

  const int lane = tid & 63, wid = tid >> 6;
  float st0[8], st1[8], st2[8], st3[8];
  #pragma unroll
  for (int cl = 0; cl < 8; ++cl) {
    const int co = co0 + cl;
    float a0, a1, a2, a3;
    a0 = a1 = a2 = a3 = b1[co];
    #pragma unroll
    for (int ci = 0; ci < 3; ++ci)
      #pragma unroll
      for (int ky = 0; ky < 3; ++ky)
        #pragma unroll
        for (int kx = 0; kx < 3; ++kx) {
          float w = w1[co * 27 + ci * 9 + ky * 3 + kx];
          a0 = fmaf(xv[ci * 18 + (0 + ky) * 3 + kx], w, a0);
          a1 = fmaf(xv[ci * 18 + (1 + ky) * 3 + kx], w, a1);
          a2 = fmaf(xv[ci * 18 + (2 + ky) * 3 + kx], w, a2);
          a3 = fmaf(xv[ci * 18 + (3 + ky) * 3 + kx], w, a3);
        }
    st0[cl] = a0; st1[cl] = a1; st2[cl] = a2; st3[cl] = a3;
    float s = a0 + a1 + a2 + a3;
    float q = fmaf(a0, a0, fmaf(a1, a1, fmaf(a2, a2, a3 * a3)));
    #pragma unroll
    for (int o = 32; o > 0; o >>= 1) {
      s += __shfl_down(s, o, 64);
      q += __shfl_down(q, o, 64);
    }
    if (lane == 0) { red[wid * 16 + cl * 2] = s; red[wid * 16 + cl * 2 + 1] = q; }
  }

  // Store y1 plane (bf16): one int4 (8 ch) per row.
  {
    short* yb = y1 + (size_t)chalf * 8388608 + (size_t)b * 8192;
    int4 v0 = make_int4(pack2bf(st0[0], st0[1]), pack2bf(st0[2], st0[3]),
                        pack2bf(st0[4], st0[5]), pack2bf(st0[6], st0[7]));
    int4 v1 = make_int4(pack2bf(st1[0], st1[1]), pack2bf(st1[2], st1[3]),
                        pack2bf(st1[4], st1[5]), pack2bf(st1[6], st1[7]));
    int4 v2 = make_int4(pack2bf(st2[0], st2[1]), pack2bf(st2[2], st2[3]),
                        pack2bf(st2[4], st2[5]), pack2bf(st2[6], st2[7]));
    int4 v3 = make_int4(pack2bf(st3[0], st3[1]), pack2bf(st3[2], st3[3]),
                        pack2bf(st3[4], st3[5]), pack2bf(st3[6], st3[7]));
    *(int4*)(yb + ((r0 + 0) * 32 + c) * 8) = v0;
    *(int4*)(yb + ((r0 + 1) * 32 + c) * 8) = v1;
    *(int4*)(yb + ((r0 + 2) * 32 + c) * 8) = v2;
    *(int4*)(yb + ((r0 + 3) * 32 + c) * 8) = v3;
  }

  __syncthreads();
  if (tid < 32) {
    int co = tid >> 1, sel = tid & 1;
    int g = co >> 3;                    // wave group 0 (waves 0-3) or 1 (4-7)
    int cl = co & 7;
    float r = red[(g * 4 + 0) * 16 + cl * 2 + sel] +
              red[(g * 4 + 1) * 16 + cl * 2 + sel] +
              red[(g * 4 + 2) * 16 + cl * 2 + sel] +
              red[(g * 4 + 3) * 16 + cl * 2 + sel];
    partials[(co * 2 + sel) * 1024 + b] = r;
  }
}

// K2/K6: reduce partials -> scale/shift per channel.
__global__ __launch_bounds__(256) void k_bn_finalize(
    const float* __restrict__ partials, int nb, float invN,
    const float* __restrict__ gamma, const float* __restrict__ beta,
    float* __restrict__ stats, int C) {
  __shared__ float lds[4];
  int c = blockIdx.x;
  float s = 0.f, q = 0.f;
  for (int i = threadIdx.x; i < nb; i += blockDim.x) {
    s += partials[(c * 2 + 0) * nb + i];
    q += partials[(c * 2 + 1) * nb + i];
  }
  s = block_reduce_sum(s, lds);
  q = block_reduce_sum(q, lds);
  if (threadIdx.x == 0) {
    float mean = s * invN;
    float var  = q * invN - mean * mean;
    float scale = gamma[c] * rsqrtf(var + EPSV);
    stats[c]     = scale;
    stats[C + c] = beta[c] - mean * scale;
  }
}

// K34 v7: BN1+ReLU+pool1 from bf16 planar y1 + conv2 MFMA; y2 stored BF16
// packed [b][16 copair][256 pos] (stats stay fp32-exact from acc). 512 thr.
__global__ __launch_bounds__(512) void k34_pool1_conv2(
    const short* __restrict__ y1, const float* __restrict__ stats1,
    const float* __restrict__ pw, const float* __restrict__ pb,
    const short* __restrict__ wA, const float* __restrict__ b2,
    unsigned* __restrict__ y2, float* __restrict__ partials) {
  __shared__ __align__(16) short bh[12960];  // 25.92 KB: [324 cells][40]
  const int tid = threadIdx.x, b = blockIdx.x;

  // Phase A0: zero the 68 border cells (80 B = 5 int4 each).
  for (int t = tid; t < 340; t += 512) {
    int i = t / 5, part = t - i * 5;
    int r, cc;
    if (i < 18)      { r = 0;  cc = i; }
    else if (i < 36) { r = 17; cc = i - 18; }
    else { int j = i - 36; r = 1 + (j >> 1); cc = (j & 1) * 17; }
    *(int4*)&bh[(r * 18 + cc) * 40 + part * 8] = make_int4(0, 0, 0, 0);
  }

  // Phase A1: load this thread's 2x2 patch x 8 channels (bf16) from its plane.
  const int cell = tid & 255;
  const int chalf = tid >> 8;
  const int ow = cell & 15, oh = cell >> 4;
  const short* yb = y1 + (size_t)chalf * 8388608 + (size_t)b * 8192
                       + ((2 * oh) * 32 + 2 * ow) * 8;
  float va[8], vb[8], vc[8], vd[8];
  bf8_decode(*(const int4*)(yb),       va);
  bf8_decode(*(const int4*)(yb + 8),   vb);
  bf8_decode(*(const int4*)(yb + 256), vc);
  bf8_decode(*(const int4*)(yb + 264), vd);

  // Phase A2: BN + ReLU + basis_pool for 8 channels; pack bf16 (RTN) to LDS.
  {
    const float pw0 = pw[0] * 10.f, pw1 = pw[1] * 10.f;
    const float pb0 = pb[0] * 10.f, pb1 = pb[1] * 10.f;
    unsigned hiw[8];
    #pragma unroll
    for (int cl = 0; cl < 8; ++cl) {
      const int c = chalf * 8 + cl;
      const float scale = stats1[c], shift = stats1[16 + c];
      float v0 = fmaxf(fmaf(va[cl], scale, shift), 0.f);
      float v1 = fmaxf(fmaf(vb[cl], scale, shift), 0.f);
      float v2 = fmaxf(fmaf(vc[cl], scale, shift), 0.f);
      float v3 = fmaxf(fmaf(vd[cl], scale, shift), 0.f);
      float o0, o1;
      #pragma unroll
      for (int k = 0; k < 2; ++k) {
        float cw = k ? pw1 : pw0;
        float cb = k ? pb1 : pb0;
        float s0 = fmaf(v0, cw, cb), s1 = fmaf(v1, cw, cb);
        float s2 = fmaf(v2, cw, cb), s3 = fmaf(v3, cw, cb);
        float m = fmaxf(fmaxf(s0, s1), fmaxf(s2, s3));
        float e0 = __expf(s0 - m), e1 = __expf(s1 - m);
        float e2 = __expf(s2 - m), e3 = __expf(s3 - m);
        float den = e0 + e1 + e2 + e3;
        float outv = (v0 * e0 + v1 * e1 + v2 * e2 + v3 * e3) / den;
        if (k == 0) o0 = outv; else o1 = outv;
      }
      hiw[cl] = pack2bf(o0, o1);
    }
    const int pcell = (oh + 1) * 18 + (ow + 1);
    short* hp = &bh[pcell * 40 + chalf * 16];
    *(int4*)hp       = *(int4*)&hiw[0];
    *(int4*)(hp + 8) = *(int4*)&hiw[4];
  }
  __syncthreads();

  // Phase B: conv2 via bf16 MFMA (Ah + Al on single-B), read from LDS. 8 waves.
  const int l = tid & 63;
  const int w = tid >> 6;
  const int q = l >> 4;
  const int c = l & 15;
  const int rbase = w * 2;

  f32x4 acc[2][2];
  #pragma unroll
  for (int m = 0; m < 2; ++m) {
    f32x4 bj = *(const f32x4*)&b2[m * 16 + q * 4];
    acc[m][0] = bj; acc[m][1] = bj;
  }

  const bf16x8* wAf = (const bf16x8*)wA;
  for (int ky = 0; ky < 3; ++ky) {
    for (int kx = 0; kx < 3; ++kx) {
      const int s = ky * 3 + kx;
      bf16x8 a0h = wAf[((s * 2 + 0) * 2 + 0) * 64 + l];
      bf16x8 a0l = wAf[((s * 2 + 0) * 2 + 1) * 64 + l];
      bf16x8 a1h = wAf[((s * 2 + 1) * 2 + 0) * 64 + l];
      bf16x8 a1l = wAf[((s * 2 + 1) * 2 + 1) * 64 + l];
      #pragma unroll
      for (int r = 0; r < 2; ++r) {
        const int pos = (rbase + r + ky) * 18 + (c + kx);
        bf16x8 bhv = *(const bf16x8*)&bh[pos * 40 + q * 8];
        acc[0][r] = __builtin_amdgcn_mfma_f32_16x16x32_bf16(a0h, bhv, acc[0][r], 0, 0, 0);
        acc[0][r] = __builtin_amdgcn_mfma_f32_16x16x32_bf16(a0l, bhv, acc[0][r], 0, 0, 0);
        acc[1][r] = __builtin_amdgcn_mfma_f32_16x16x32_bf16(a1h, bhv, acc[1][r], 0, 0, 0);
        acc[1][r] = __builtin_amdgcn_mfma_f32_16x16x32_bf16(a1l, bhv, acc[1][r], 0, 0, 0);
      }
    }
  }

  // y2 write (bf16 pairs): copair = m*8+q*2+(j>>1), lo=j even, hi=j odd.
  {
    unsigned* yb2 = y2 + (size_t)b * 4096;
    #pragma unroll
    for (int m = 0; m < 2; ++m)
      #pragma unroll
      for (int r = 0; r < 2; ++r) {
        const int pos = (rbase + r) * 16 + c;
        yb2[(m * 8 + q * 2 + 0) * 256 + pos] = pack2bf(acc[m][r][0], acc[m][r][1]);
        yb2[(m * 8 + q * 2 + 1) * 256 + pos] = pack2bf(acc[m][r][2], acc[m][r][3]);
      }
  }

  // Fused BN2 partial stats (exact fp32) -> partials [32][2][8192], slot b*8+w.
  const int slot = b * 8 + w;
  #pragma unroll
  for (int m = 0; m < 2; ++m) {
    #pragma unroll
    for (int j = 0; j < 4; ++j) {
      float a0 = acc[m][0][j], a1 = acc[m][1][j];
      float sv = a0 + a1;
      float qv = fmaf(a0, a0, a1 * a1);
      #pragma unroll
      for (int o = 1; o <= 8; o <<= 1) {
        sv += __shfl_xor(sv, o, 64);
        qv += __shfl_xor(qv, o, 64);
      }
      if (c == 0) {
        int co = m * 16 + q * 4 + j;
        partials[(co * 2 + 0) * 8192 + slot] = sv;
        partials[(co * 2 + 1) * 8192 + slot] = qv;
      }
    }
  }
}

// K78: fused BN2-finalized pool2 + FC, reading bf16-packed y2. One block/image.
__global__ __launch_bounds__(256) void k78_pool2_fc(
    const unsigned* __restrict__ y2, const float* __restrict__ stats2,
    const float* __restrict__ pw, const float* __restrict__ pb,
    const float* __restrict__ fcw, const float* __restrict__ fcb,
    float* __restrict__ out) {
  __shared__ float h2s[4096];
  __shared__ float red[40];
  const int tid = threadIdx.x;
  const int b = blockIdx.x;

  {
    const int c = tid >> 3, oh = tid & 7;
    const int half = c & 1;
    const float scale = stats2[c], shift = stats2[32 + c];
    const float pw0 = pw[0] * 10.f, pw1 = pw[1] * 10.f;
    const float pb0 = pb[0] * 10.f, pb1 = pb[1] * 10.f;
    const unsigned* yb = y2 + (size_t)b * 4096 + (c >> 1) * 256 + (2 * oh) * 16;
    unsigned ua[16], ub[16];
    #pragma unroll
    for (int k = 0; k < 4; ++k) {
      *(int4*)&ua[k * 4] = ((const int4*)yb)[k];
      *(int4*)&ub[k * 4] = ((const int4*)(yb + 16))[k];
    }
    float rowa[16], rowb[16];
    #pragma unroll
    for (int i = 0; i < 16; ++i) {
      rowa[i] = half ? __uint_as_float(ua[i] & 0xffff0000u) : __uint_as_float(ua[i] << 16);
      rowb[i] = half ? __uint_as_float(ub[i] & 0xffff0000u) : __uint_as_float(ub[i] << 16);
    }
    #pragma unroll
    for (int ow = 0; ow < 8; ++ow) {
      float v0 = fmaxf(fmaf(rowa[2 * ow],     scale, shift), 0.f);
      float v1 = fmaxf(fmaf(rowa[2 * ow + 1], scale, shift), 0.f);
      float v2 = fmaxf(fmaf(rowb[2 * ow],     scale, shift), 0.f);
      float v3 = fmaxf(fmaf(rowb[2 * ow + 1], scale, shift), 0.f);
      #pragma unroll
      for (int k = 0; k < 2; ++k) {
        float cw = k ? pw1 : pw0;
        float cb = k ? pb1 : pb0;
        float s0 = fmaf(v0, cw, cb), s1 = fmaf(v1, cw, cb);
        float s2 = fmaf(v2, cw, cb), s3 = fmaf(v3, cw, cb);
        float m = fmaxf(fmaxf(s0, s1), fmaxf(s2, s3));
        float e0 = __expf(s0 - m), e1 = __expf(s1 - m);
        float e2 = __expf(s2 - m), e3 = __expf(s3 - m);
        float den = e0 + e1 + e2 + e3;
        h2s[(c * 2 + k) * 64 + oh * 8 + ow] =
            (v0 * e0 + v1 * e1 + v2 * e2 + v3 * e3) / den;
      }
    }
  }
  __syncthreads();

  float acc[10];
  #pragma unroll
  for (int j = 0; j < 10; ++j) acc[j] = 0.f;
  #pragma unroll
  for (int k = 0; k < 16; ++k) {
    float hv = h2s[k * 256 + tid];
    #pragma unroll
    for (int j = 0; j < 10; ++j)
      acc[j] = fmaf(hv, fcw[j * 4096 + k * 256 + tid], acc[j]);
  }
  const int lane = tid & 63, wid = tid >> 6;
  #pragma unroll
  for (int j = 0; j < 10; ++j) {
    float v = acc[j];
    #pragma unroll
    for (int off = 32; off > 0; off >>= 1) v += __shfl_down(v, off, 64);
    if (lane == 0) red[wid * 10 + j] = v;
  }
  __syncthreads();
  if (tid < 10) {
    out[b * 10 + tid] = red[tid] + red[10 + tid] + red[20 + tid] + red[30 + tid] + fcb[tid];
  }
}

extern "C" void kernel_launch(void* const* d_in, const int* in_sizes, int n_in,
                              void* d_out, int out_size, void* d_ws, size_t ws_size,
                              hipStream_t stream) {
  (void)in_sizes; (void)n_in; (void)out_size; (void)ws_size;
  const float* x   = (const float*)d_in[0];
  const float* w1  = (const float*)d_in[1];
  const float* b1  = (const float*)d_in[2];
  const float* g1  = (const float*)d_in[3];
  const float* be1 = (const float*)d_in[4];
  const float* pw1 = (const float*)d_in[5];
  const float* pb1 = (const float*)d_in[6];
  const float* w2  = (const float*)d_in[7];
  const float* b2  = (const float*)d_in[8];
  const float* g2  = (const float*)d_in[9];
  const float* be2 = (const float*)d_in[10];
  const float* pw2 = (const float*)d_in[11];
  const float* pb2 = (const float*)d_in[12];
  const float* fcw = (const float*)d_in[13];
  const float* fcb = (const float*)d_in[14];
  float* out = (float*)d_out;

  char* ws = (char*)d_ws;
  short* y1       = (short*)(ws);                          // 32 MiB bf16 planar
  unsigned* y2    = (unsigned*)(ws + 33554432);            // 16 MiB bf16 pairs
  float* partials = (float*)(ws + 33554432 + 16777216);    // 2 MiB ([32][2][8192])
  short* wA       = (short*)(ws + 33554432 + 16777216 + 2097152);  // 36 KiB
  float* stats1   = (float*)(ws + 33554432 + 16777216 + 2097152 + 36864);
  float* stats2   = stats1 + 32;

  k1_conv1_stats<<<1024, 512, 0, stream>>>(x, w1, b1, partials, w2, wA, y1);
  k_bn_finalize<<<16, 256, 0, stream>>>(partials, 1024, 1.f / 1048576.f, g1, be1, stats1, 16);
  k34_pool1_conv2<<<1024, 512, 0, stream>>>(y1, stats1, pw1, pb1, wA, b2, y2, partials);
  k_bn_finalize<<<32, 256, 0, stream>>>(partials, 8192, 1.f / 262144.f, g2, be2, stats2, 32);
  k78_pool2_fc<<<1024, 256, 0, stream>>>(y2, stats2, pw2, pb2, fcw, fcb, out);
}

// Round 26
// 86.262 us; speedup vs baseline: 1.0939x; 1.0939x over previous
//
#include <hip/hip_runtime.h>

#define EPSV 1e-5f

typedef __attribute__((ext_vector_type(8))) short bf16x8;
typedef __attribute__((ext_vector_type(4))) float f32x4;

__device__ __forceinline__ unsigned short f2bf(float x) {
  unsigned u = __float_as_uint(x);
  unsigned r = (u + 0x7FFFu + ((u >> 16) & 1u)) >> 16;
  return (unsigned short)r;
}

__device__ __forceinline__ unsigned pack2bf(float a, float b) {
  return (unsigned)f2bf(a) | ((unsigned)f2bf(b) << 16);
}

__device__ __forceinline__ void bf8_decode(int4 v, float* dst) {
  unsigned u0 = (unsigned)v.x, u1 = (unsigned)v.y, u2 = (unsigned)v.z, u3 = (unsigned)v.w;
  dst[0] = __uint_as_float(u0 << 16); dst[1] = __uint_as_float(u0 & 0xffff0000u);
  dst[2] = __uint_as_float(u1 << 16); dst[3] = __uint_as_float(u1 & 0xffff0000u);
  dst[4] = __uint_as_float(u2 << 16); dst[5] = __uint_as_float(u2 & 0xffff0000u);
  dst[6] = __uint_as_float(u3 << 16); dst[7] = __uint_as_float(u3 & 0xffff0000u);
}

__device__ __forceinline__ float block_reduce_sum(float v, float* lds) {
  #pragma unroll
  for (int off = 32; off > 0; off >>= 1) v += __shfl_down(v, off, 64);
  int lane = threadIdx.x & 63;
  int wid  = threadIdx.x >> 6;
  __syncthreads();
  if (lane == 0) lds[wid] = v;
  __syncthreads();
  float r = 0.f;
  if (threadIdx.x == 0) {
    int nw = blockDim.x >> 6;
    for (int i = 0; i < nw; ++i) r += lds[i];
  }
  return r;
}

// Stage x[b] (3x32x32) into zero-padded LDS [3][34][34] floats (256 thr).
__device__ __forceinline__ void stage_x(const float* __restrict__ x, float* xt, int b, int tid) {
  {
    float4* t4 = (float4*)xt;
    #pragma unroll
    for (int i = 0; i < 4; ++i) {
      int idx = i * 256 + tid;
      if (idx < 867) t4[idx] = make_float4(0.f, 0.f, 0.f, 0.f);
    }
  }
  __syncthreads();
  {
    const float4* x4 = (const float4*)(x + b * 3072);
    #pragma unroll
    for (int k = 0; k < 3; ++k) {
      int e4 = k * 256 + tid;
      float4 v = x4[e4];
      int w0 = e4 * 4;
      int ch = w0 >> 10;
      int pos = w0 & 1023;
      int r = pos >> 5, c = pos & 31;
      int base = ch * 1156 + (r + 1) * 34 + (c + 1);
      xt[base] = v.x; xt[base + 1] = v.y; xt[base + 2] = v.z; xt[base + 3] = v.w;
    }
  }
  __syncthreads();
}

// K1: conv1 + stats partials + store y1 BF16 PLANAR [plane=y][b][1024 pos][8ch].
__global__ __launch_bounds__(256) void k1_conv1_stats(
    const float* __restrict__ x, const float* __restrict__ w1, const float* __restrict__ b1,
    float* __restrict__ partials /* [16][2][1024] */,
    const float* __restrict__ w2, short* __restrict__ wA, short* __restrict__ y1) {
  __shared__ float xt[3468];
  __shared__ float red[64];
  const int tid = threadIdx.x, b = blockIdx.x;
  const int co0 = blockIdx.y * 8;

  if (b == 0) {
    for (int i = tid + blockIdx.y * 9216; i < (blockIdx.y + 1) * 9216; i += 256) {
      int e = i & 7, l = (i >> 3) & 63, p = (i >> 9) & 1, m = (i >> 10) & 1, s = i >> 11;
      int co = m * 16 + (l & 15);
      int ci = (l >> 4) * 8 + e;
      int ky = s / 3, kx = s - ky * 3;
      float wv = w2[((co * 32 + ci) * 3 + ky) * 3 + kx];
      unsigned short h = f2bf(wv);
      unsigned short val = p ? f2bf(wv - __uint_as_float((unsigned)h << 16)) : h;
      wA[i] = (short)val;
    }
  }

  stage_x(x, xt, b, tid);

  const int c = tid & 31, r0 = (tid >> 5) * 4;
  const int sbase = r0 * 34 + c;
  float xv[54];
  #pragma unroll
  for (int ci = 0; ci < 3; ++ci)
    #pragma unroll
    for (int dr = 0; dr < 6; ++dr)
      #pragma unroll
      for (int dx = 0; dx < 3; ++dx)
        xv[ci * 18 + dr * 3 + dx] = xt[ci * 1156 + sbase + dr * 34 + dx];

  const int lane = tid & 63, wid = tid >> 6;
  float st0[8], st1[8], st2[8], st3[8];
  #pragma unroll
  for (int cl = 0; cl < 8; ++cl) {
    const int co = co0 + cl;
    float a0, a1, a2, a3;
    a0 = a1 = a2 = a3 = b1[co];
    #pragma unroll
    for (int ci = 0; ci < 3; ++ci)
      #pragma unroll
      for (int ky = 0; ky < 3; ++ky)
        #pragma unroll
        for (int kx = 0; kx < 3; ++kx) {
          float w = w1[co * 27 + ci * 9 + ky * 3 + kx];
          a0 = fmaf(xv[ci * 18 + (0 + ky) * 3 + kx], w, a0);
          a1 = fmaf(xv[ci * 18 + (1 + ky) * 3 + kx], w, a1);
          a2 = fmaf(xv[ci * 18 + (2 + ky) * 3 + kx], w, a2);
          a3 = fmaf(xv[ci * 18 + (3 + ky) * 3 + kx], w, a3);
        }
    st0[cl] = a0; st1[cl] = a1; st2[cl] = a2; st3[cl] = a3;
    float s = a0 + a1 + a2 + a3;
    float q = fmaf(a0, a0, fmaf(a1, a1, fmaf(a2, a2, a3 * a3)));
    #pragma unroll
    for (int o = 32; o > 0; o >>= 1) {
      s += __shfl_down(s, o, 64);
      q += __shfl_down(q, o, 64);
    }
    if (lane == 0) { red[wid * 16 + cl * 2] = s; red[wid * 16 + cl * 2 + 1] = q; }
  }

  {
    short* yb = y1 + (size_t)blockIdx.y * 8388608 + (size_t)b * 8192;
    int4 v0 = make_int4(pack2bf(st0[0], st0[1]), pack2bf(st0[2], st0[3]),
                        pack2bf(st0[4], st0[5]), pack2bf(st0[6], st0[7]));
    int4 v1 = make_int4(pack2bf(st1[0], st1[1]), pack2bf(st1[2], st1[3]),
                        pack2bf(st1[4], st1[5]), pack2bf(st1[6], st1[7]));
    int4 v2 = make_int4(pack2bf(st2[0], st2[1]), pack2bf(st2[2], st2[3]),
                        pack2bf(st2[4], st2[5]), pack2bf(st2[6], st2[7]));
    int4 v3 = make_int4(pack2bf(st3[0], st3[1]), pack2bf(st3[2], st3[3]),
                        pack2bf(st3[4], st3[5]), pack2bf(st3[6], st3[7]));
    *(int4*)(yb + ((r0 + 0) * 32 + c) * 8) = v0;
    *(int4*)(yb + ((r0 + 1) * 32 + c) * 8) = v1;
    *(int4*)(yb + ((r0 + 2) * 32 + c) * 8) = v2;
    *(int4*)(yb + ((r0 + 3) * 32 + c) * 8) = v3;
  }

  __syncthreads();
  if (tid < 16) {
    int cl = tid >> 1, sel = tid & 1;
    float r = red[cl * 2 + sel] + red[16 + cl * 2 + sel] +
              red[32 + cl * 2 + sel] + red[48 + cl * 2 + sel];
    partials[((co0 + cl) * 2 + sel) * 1024 + b] = r;
  }
}

// K2/K6: reduce partials -> scale/shift per channel.
__global__ __launch_bounds__(256) void k_bn_finalize(
    const float* __restrict__ partials, int nb, float invN,
    const float* __restrict__ gamma, const float* __restrict__ beta,
    float* __restrict__ stats, int C) {
  __shared__ float lds[4];
  int c = blockIdx.x;
  float s = 0.f, q = 0.f;
  for (int i = threadIdx.x; i < nb; i += blockDim.x) {
    s += partials[(c * 2 + 0) * nb + i];
    q += partials[(c * 2 + 1) * nb + i];
  }
  s = block_reduce_sum(s, lds);
  q = block_reduce_sum(q, lds);
  if (threadIdx.x == 0) {
    float mean = s * invN;
    float var  = q * invN - mean * mean;
    float scale = gamma[c] * rsqrtf(var + EPSV);
    stats[c]     = scale;
    stats[C + c] = beta[c] - mean * scale;
  }
}

// K34 v7: BN1+ReLU+pool1 from bf16 planar y1 + conv2 MFMA; y2 stored BF16
// packed [b][16 copair][256 pos] (stats stay fp32-exact from acc). 512 thr.
__global__ __launch_bounds__(512) void k34_pool1_conv2(
    const short* __restrict__ y1, const float* __restrict__ stats1,
    const float* __restrict__ pw, const float* __restrict__ pb,
    const short* __restrict__ wA, const float* __restrict__ b2,
    unsigned* __restrict__ y2, float* __restrict__ partials) {
  __shared__ __align__(16) short bh[12960];  // 25.92 KB: [324 cells][40]
  const int tid = threadIdx.x, b = blockIdx.x;

  // Phase A0: zero the 68 border cells (80 B = 5 int4 each).
  for (int t = tid; t < 340; t += 512) {
    int i = t / 5, part = t - i * 5;
    int r, cc;
    if (i < 18)      { r = 0;  cc = i; }
    else if (i < 36) { r = 17; cc = i - 18; }
    else { int j = i - 36; r = 1 + (j >> 1); cc = (j & 1) * 17; }
    *(int4*)&bh[(r * 18 + cc) * 40 + part * 8] = make_int4(0, 0, 0, 0);
  }

  // Phase A1: load this thread's 2x2 patch x 8 channels (bf16) from its plane.
  const int cell = tid & 255;
  const int chalf = tid >> 8;
  const int ow = cell & 15, oh = cell >> 4;
  const short* yb = y1 + (size_t)chalf * 8388608 + (size_t)b * 8192
                       + ((2 * oh) * 32 + 2 * ow) * 8;
  float va[8], vb[8], vc[8], vd[8];
  bf8_decode(*(const int4*)(yb),       va);
  bf8_decode(*(const int4*)(yb + 8),   vb);
  bf8_decode(*(const int4*)(yb + 256), vc);
  bf8_decode(*(const int4*)(yb + 264), vd);

  // Phase A2: BN + ReLU + basis_pool for 8 channels; pack bf16 (RTN) to LDS.
  {
    const float pw0 = pw[0] * 10.f, pw1 = pw[1] * 10.f;
    const float pb0 = pb[0] * 10.f, pb1 = pb[1] * 10.f;
    unsigned hiw[8];
    #pragma unroll
    for (int cl = 0; cl < 8; ++cl) {
      const int c = chalf * 8 + cl;
      const float scale = stats1[c], shift = stats1[16 + c];
      float v0 = fmaxf(fmaf(va[cl], scale, shift), 0.f);
      float v1 = fmaxf(fmaf(vb[cl], scale, shift), 0.f);
      float v2 = fmaxf(fmaf(vc[cl], scale, shift), 0.f);
      float v3 = fmaxf(fmaf(vd[cl], scale, shift), 0.f);
      float o0, o1;
      #pragma unroll
      for (int k = 0; k < 2; ++k) {
        float cw = k ? pw1 : pw0;
        float cb = k ? pb1 : pb0;
        float s0 = fmaf(v0, cw, cb), s1 = fmaf(v1, cw, cb);
        float s2 = fmaf(v2, cw, cb), s3 = fmaf(v3, cw, cb);
        float m = fmaxf(fmaxf(s0, s1), fmaxf(s2, s3));
        float e0 = __expf(s0 - m), e1 = __expf(s1 - m);
        float e2 = __expf(s2 - m), e3 = __expf(s3 - m);
        float den = e0 + e1 + e2 + e3;
        float outv = (v0 * e0 + v1 * e1 + v2 * e2 + v3 * e3) / den;
        if (k == 0) o0 = outv; else o1 = outv;
      }
      hiw[cl] = pack2bf(o0, o1);
    }
    const int pcell = (oh + 1) * 18 + (ow + 1);
    short* hp = &bh[pcell * 40 + chalf * 16];
    *(int4*)hp       = *(int4*)&hiw[0];
    *(int4*)(hp + 8) = *(int4*)&hiw[4];
  }
  __syncthreads();

  // Phase B: conv2 via bf16 MFMA (Ah + Al on single-B), read from LDS. 8 waves.
  const int l = tid & 63;
  const int w = tid >> 6;
  const int q = l >> 4;
  const int c = l & 15;
  const int rbase = w * 2;

  f32x4 acc[2][2];
  #pragma unroll
  for (int m = 0; m < 2; ++m) {
    f32x4 bj = *(const f32x4*)&b2[m * 16 + q * 4];
    acc[m][0] = bj; acc[m][1] = bj;
  }

  const bf16x8* wAf = (const bf16x8*)wA;
  for (int ky = 0; ky < 3; ++ky) {
    for (int kx = 0; kx < 3; ++kx) {
      const int s = ky * 3 + kx;
      bf16x8 a0h = wAf[((s * 2 + 0) * 2 + 0) * 64 + l];
      bf16x8 a0l = wAf[((s * 2 + 0) * 2 + 1) * 64 + l];
      bf16x8 a1h = wAf[((s * 2 + 1) * 2 + 0) * 64 + l];
      bf16x8 a1l = wAf[((s * 2 + 1) * 2 + 1) * 64 + l];
      #pragma unroll
      for (int r = 0; r < 2; ++r) {
        const int pos = (rbase + r + ky) * 18 + (c + kx);
        bf16x8 bhv = *(const bf16x8*)&bh[pos * 40 + q * 8];
        acc[0][r] = __builtin_amdgcn_mfma_f32_16x16x32_bf16(a0h, bhv, acc[0][r], 0, 0, 0);
        acc[0][r] = __builtin_amdgcn_mfma_f32_16x16x32_bf16(a0l, bhv, acc[0][r], 0, 0, 0);
        acc[1][r] = __builtin_amdgcn_mfma_f32_16x16x32_bf16(a1h, bhv, acc[1][r], 0, 0, 0);
        acc[1][r] = __builtin_amdgcn_mfma_f32_16x16x32_bf16(a1l, bhv, acc[1][r], 0, 0, 0);
      }
    }
  }

  // y2 write (bf16 pairs): copair = m*8+q*2+(j>>1), lo=j even, hi=j odd.
  {
    unsigned* yb2 = y2 + (size_t)b * 4096;
    #pragma unroll
    for (int m = 0; m < 2; ++m)
      #pragma unroll
      for (int r = 0; r < 2; ++r) {
        const int pos = (rbase + r) * 16 + c;
        yb2[(m * 8 + q * 2 + 0) * 256 + pos] = pack2bf(acc[m][r][0], acc[m][r][1]);
        yb2[(m * 8 + q * 2 + 1) * 256 + pos] = pack2bf(acc[m][r][2], acc[m][r][3]);
      }
  }

  // Fused BN2 partial stats (exact fp32) -> partials [32][2][8192], slot b*8+w.
  const int slot = b * 8 + w;
  #pragma unroll
  for (int m = 0; m < 2; ++m) {
    #pragma unroll
    for (int j = 0; j < 4; ++j) {
      float a0 = acc[m][0][j], a1 = acc[m][1][j];
      float sv = a0 + a1;
      float qv = fmaf(a0, a0, a1 * a1);
      #pragma unroll
      for (int o = 1; o <= 8; o <<= 1) {
        sv += __shfl_xor(sv, o, 64);
        qv += __shfl_xor(qv, o, 64);
      }
      if (c == 0) {
        int co = m * 16 + q * 4 + j;
        partials[(co * 2 + 0) * 8192 + slot] = sv;
        partials[(co * 2 + 1) * 8192 + slot] = qv;
      }
    }
  }
}

// K78: fused BN2-finalized pool2 + FC, reading bf16-packed y2. One block/image.
__global__ __launch_bounds__(256) void k78_pool2_fc(
    const unsigned* __restrict__ y2, const float* __restrict__ stats2,
    const float* __restrict__ pw, const float* __restrict__ pb,
    const float* __restrict__ fcw, const float* __restrict__ fcb,
    float* __restrict__ out) {
  __shared__ float h2s[4096];
  __shared__ float red[40];
  const int tid = threadIdx.x;
  const int b = blockIdx.x;

  {
    const int c = tid >> 3, oh = tid & 7;
    const int half = c & 1;
    const float scale = stats2[c], shift = stats2[32 + c];
    const float pw0 = pw[0] * 10.f, pw1 = pw[1] * 10.f;
    const float pb0 = pb[0] * 10.f, pb1 = pb[1] * 10.f;
    const unsigned* yb = y2 + (size_t)b * 4096 + (c >> 1) * 256 + (2 * oh) * 16;
    unsigned ua[16], ub[16];
    #pragma unroll
    for (int k = 0; k < 4; ++k) {
      *(int4*)&ua[k * 4] = ((const int4*)yb)[k];
      *(int4*)&ub[k * 4] = ((const int4*)(yb + 16))[k];
    }
    float rowa[16], rowb[16];
    #pragma unroll
    for (int i = 0; i < 16; ++i) {
      rowa[i] = half ? __uint_as_float(ua[i] & 0xffff0000u) : __uint_as_float(ua[i] << 16);
      rowb[i] = half ? __uint_as_float(ub[i] & 0xffff0000u) : __uint_as_float(ub[i] << 16);
    }
    #pragma unroll
    for (int ow = 0; ow < 8; ++ow) {
      float v0 = fmaxf(fmaf(rowa[2 * ow],     scale, shift), 0.f);
      float v1 = fmaxf(fmaf(rowa[2 * ow + 1], scale, shift), 0.f);
      float v2 = fmaxf(fmaf(rowb[2 * ow],     scale, shift), 0.f);
      float v3 = fmaxf(fmaf(rowb[2 * ow + 1], scale, shift), 0.f);
      #pragma unroll
      for (int k = 0; k < 2; ++k) {
        float cw = k ? pw1 : pw0;
        float cb = k ? pb1 : pb0;
        float s0 = fmaf(v0, cw, cb), s1 = fmaf(v1, cw, cb);
        float s2 = fmaf(v2, cw, cb), s3 = fmaf(v3, cw, cb);
        float m = fmaxf(fmaxf(s0, s1), fmaxf(s2, s3));
        float e0 = __expf(s0 - m), e1 = __expf(s1 - m);
        float e2 = __expf(s2 - m), e3 = __expf(s3 - m);
        float den = e0 + e1 + e2 + e3;
        h2s[(c * 2 + k) * 64 + oh * 8 + ow] =
            (v0 * e0 + v1 * e1 + v2 * e2 + v3 * e3) / den;
      }
    }
  }
  __syncthreads();

  float acc[10];
  #pragma unroll
  for (int j = 0; j < 10; ++j) acc[j] = 0.f;
  #pragma unroll
  for (int k = 0; k < 16; ++k) {
    float hv = h2s[k * 256 + tid];
    #pragma unroll
    for (int j = 0; j < 10; ++j)
      acc[j] = fmaf(hv, fcw[j * 4096 + k * 256 + tid], acc[j]);
  }
  const int lane = tid & 63, wid = tid >> 6;
  #pragma unroll
  for (int j = 0; j < 10; ++j) {
    float v = acc[j];
    #pragma unroll
    for (int off = 32; off > 0; off >>= 1) v += __shfl_down(v, off, 64);
    if (lane == 0) red[wid * 10 + j] = v;
  }
  __syncthreads();
  if (tid < 10) {
    out[b * 10 + tid] = red[tid] + red[10 + tid] + red[20 + tid] + red[30 + tid] + fcb[tid];
  }
}

extern "C" void kernel_launch(void* const* d_in, const int* in_sizes, int n_in,
                              void* d_out, int out_size, void* d_ws, size_t ws_size,
                              hipStream_t stream) {
  (void)in_sizes; (void)n_in; (void)out_size; (void)ws_size;
  const float* x   = (const float*)d_in[0];
  const float* w1  = (const float*)d_in[1];
  const float* b1  = (const float*)d_in[2];
  const float* g1  = (const float*)d_in[3];
  const float* be1 = (const float*)d_in[4];
  const float* pw1 = (const float*)d_in[5];
  const float* pb1 = (const float*)d_in[6];
  const float* w2  = (const float*)d_in[7];
  const float* b2  = (const float*)d_in[8];
  const float* g2  = (const float*)d_in[9];
  const float* be2 = (const float*)d_in[10];
  const float* pw2 = (const float*)d_in[11];
  const float* pb2 = (const float*)d_in[12];
  const float* fcw = (const float*)d_in[13];
  const float* fcb = (const float*)d_in[14];
  float* out = (float*)d_out;

  char* ws = (char*)d_ws;
  short* y1       = (short*)(ws);                          // 32 MiB bf16 planar
  unsigned* y2    = (unsigned*)(ws + 33554432);            // 16 MiB bf16 pairs
  float* partials = (float*)(ws + 33554432 + 16777216);    // 2 MiB ([32][2][8192])
  short* wA       = (short*)(ws + 33554432 + 16777216 + 2097152);  // 36 KiB
  float* stats1   = (float*)(ws + 33554432 + 16777216 + 2097152 + 36864);
  float* stats2   = stats1 + 32;

  dim3 g2d(1024, 2);
  k1_conv1_stats<<<g2d, 256, 0, stream>>>(x, w1, b1, partials, w2, wA, y1);
  k_bn_finalize<<<16, 256, 0, stream>>>(partials, 1024, 1.f / 1048576.f, g1, be1, stats1, 16);
  k34_pool1_conv2<<<1024, 512, 0, stream>>>(y1, stats1, pw1, pb1, wA, b2, y2, partials);
  k_bn_finalize<<<32, 256, 0, stream>>>(partials, 8192, 1.f / 262144.f, g2, be2, stats2, 32);
  k78_pool2_fc<<<1024, 256, 0, stream>>>(y2, stats2, pw2, pb2, fcw, fcb, out);
}